// Round 6
// baseline (374.644 us; speedup 1.0000x reference)
//
#include <hip/hip_runtime.h>

// GruBlock round 6: MFMA recurrence, 16 sequences per wave.
// 384 blocks x 64 threads (1 wave). Block = (group of 16 h-rows, direction).
// Per step: gh = whh @ H  via 6x mfma_f32_16x16x32_f16 (A=whh tiles f16,
// B=h[32k][16seq] f16 from LDS ring, C-init = projection pre-acts from s_pre).
// Projection per 4-step chunk: pre = W2 @ x (W2 = wih@conv_w folded, f16),
// same MFMA family, biases via C-init. Zero barriers (single-wave blocks).

typedef _Float16 f16x8 __attribute__((ext_vector_type(8)));
typedef _Float16 f16x4 __attribute__((ext_vector_type(4)));
typedef __fp16   pk16  __attribute__((ext_vector_type(2)));
typedef float    f32x4 __attribute__((ext_vector_type(4)));

#define HWSTRIDE 7680   // 48*160
#define NCH 40          // 160 steps / 4
#define WS_BIAS_OFF 24576

__global__ void fold_weights(const float* __restrict__ conv_w,
                             const float* __restrict__ conv_b,
                             const float* __restrict__ wih_f,
                             const float* __restrict__ bih_f,
                             const float* __restrict__ bhh_f,
                             const float* __restrict__ wih_b,
                             const float* __restrict__ bih_b,
                             const float* __restrict__ bhh_b,
                             void* wsv)
{
    _Float16* W2 = (_Float16*)wsv;
    float* bias = (float*)((char*)wsv + WS_BIAS_OFF);
    const int idx = blockIdx.x * 256 + threadIdx.x;
    if (idx < 12288) {
        const int d = idx / 6144, r = idx % 6144, g = r / 64, c = r % 64;
        const float* wih = d ? wih_b : wih_f;
        float acc = 0.f;
        for (int o = 0; o < 64; ++o) acc += wih[g * 64 + o] * conv_w[o * 64 + c];
        W2[idx] = (_Float16)acc;
    } else if (idx < 12288 + 256) {
        const int e = idx - 12288;
        const int d = e >> 7, rr = e & 127, kind = rr >> 5, j = rr & 31;
        const float* wih = d ? wih_b : wih_f;
        const float* bih = d ? bih_b : bih_f;
        const float* bhh = d ? bhh_b : bhh_f;
        float v;
        if (kind == 0 || kind == 1) {
            const int g = j + kind * 32;
            float b2 = bih[g];
            for (int o = 0; o < 64; ++o) b2 += wih[g * 64 + o] * conv_b[o];
            v = b2 + bhh[g];
        } else if (kind == 2) {
            const int g = j + 64;
            float b2 = bih[g];
            for (int o = 0; o < 64; ++o) b2 += wih[g * 64 + o] * conv_b[o];
            v = b2;
        } else {
            v = bhh[j + 64];
        }
        bias[(d * 4 + kind) * 32 + j] = v;
    }
}

static __device__ __forceinline__ unsigned pkh(float a, float b) {
    pk16 p = __builtin_amdgcn_cvt_pkrtz(a, b);
    return __builtin_bit_cast(unsigned, p);
}

__global__ __launch_bounds__(64, 1)
void gru_fused5(const float* __restrict__ x,
                const float* __restrict__ whh_f,
                const float* __restrict__ whh_b,
                const void* __restrict__ wsv,
                float* __restrict__ out)
{
    __shared__ _Float16 x_lds[2][64][17][4];    // 17408 B [buf][c][s(pad17)][tt]
    __shared__ _Float16 s_pre[2][4][16][104];   // 26624 B [buf][tt][s][gate(pad104)]
    __shared__ _Float16 hring[4][16][40];       // 5120 B  [t&3][s][j(pad40)]

    const int d     = blockIdx.x & 1;
    const int group = blockIdx.x >> 1;
    const int b     = group / 3;
    const int h0    = (group % 3) * 16;
    const int lane  = threadIdx.x;
    const int q     = lane >> 4;     // k-block / row-quad selector
    const int s16   = lane & 15;     // sequence (n-col) / A-row (m)

    const float* xb = x + (size_t)b * 64 * HWSTRIDE + (size_t)h0 * 160;

    // ---------------- persistent weights ----------------
    const _Float16* W2 = (const _Float16*)wsv + (size_t)d * 96 * 64;
    f16x8 W2A[6][2];
    #pragma unroll
    for (int gt = 0; gt < 6; ++gt)
        #pragma unroll
        for (int kt = 0; kt < 2; ++kt)
            W2A[gt][kt] = *(const f16x8*)&W2[(gt * 16 + s16) * 64 + kt * 32 + q * 8];

    const float* whh = d ? whh_b : whh_f;
    f16x8 whhA[6];
    #pragma unroll
    for (int gt = 0; gt < 6; ++gt)
        #pragma unroll
        for (int e = 0; e < 8; ++e)
            whhA[gt][e] = (_Float16)whh[(gt * 16 + s16) * 32 + q * 8 + e];

    const float* bias = (const float*)((const char*)wsv + WS_BIAS_OFF) + d * 128;
    float biasC[6][4];   // projection C-init: gt0,1=kind0(r); gt2,3=kind1(z); gt4,5=kind2(n)
    #pragma unroll
    for (int r = 0; r < 4; ++r) {
        biasC[0][r] = bias[      4 * q + r];
        biasC[1][r] = bias[ 16 + 4 * q + r];
        biasC[2][r] = bias[ 32 + 4 * q + r];
        biasC[3][r] = bias[ 48 + 4 * q + r];
        biasC[4][r] = bias[ 64 + 4 * q + r];
        biasC[5][r] = bias[ 80 + 4 * q + r];
    }
    float bhN[2][4];     // scan C-init for n-gates (bhh_n)
    #pragma unroll
    for (int r = 0; r < 4; ++r) {
        bhN[0][r] = bias[ 96 + 4 * q + r];
        bhN[1][r] = bias[112 + 4 * q + r];
    }

    // ---------------- staging helpers ----------------
    float4 pf[16];
    auto stage_issue = [&](int cn) {
        const int w0 = d ? (156 - cn * 4) : (cn * 4);
        const float* base = xb + s16 * 160 + w0;
        #pragma unroll
        for (int i = 0; i < 16; ++i)
            pf[i] = *(const float4*)(base + (size_t)(i * 4 + q) * HWSTRIDE);
    };
    auto stage_write = [&](int buf) {
        #pragma unroll
        for (int i = 0; i < 16; ++i) {
            const int c = i * 4 + q;
            uint2 v;
            if (d == 0) { v.x = pkh(pf[i].x, pf[i].y); v.y = pkh(pf[i].z, pf[i].w); }
            else        { v.x = pkh(pf[i].w, pf[i].z); v.y = pkh(pf[i].y, pf[i].x); }
            *(uint2*)&x_lds[buf][c][s16][0] = v;
        }
    };
    auto project = [&](int buf) {
        #pragma unroll
        for (int tt = 0; tt < 4; ++tt) {
            f16x8 B0, B1;
            #pragma unroll
            for (int e = 0; e < 8; ++e) {
                B0[e] = x_lds[buf][     q * 8 + e][s16][tt];
                B1[e] = x_lds[buf][32 + q * 8 + e][s16][tt];
            }
            #pragma unroll
            for (int gt = 0; gt < 6; ++gt) {
                f32x4 acc = {biasC[gt][0], biasC[gt][1], biasC[gt][2], biasC[gt][3]};
                acc = __builtin_amdgcn_mfma_f32_16x16x32_f16(W2A[gt][0], B0, acc, 0, 0, 0);
                acc = __builtin_amdgcn_mfma_f32_16x16x32_f16(W2A[gt][1], B1, acc, 0, 0, 0);
                uint2 v; v.x = pkh(acc[0], acc[1]); v.y = pkh(acc[2], acc[3]);
                *(uint2*)&s_pre[buf][tt][s16][gt * 16 + 4 * q] = v;
            }
        }
    };

    // ---------------- prologue ----------------
    float hprev[8];
    #pragma unroll
    for (int u = 0; u < 8; ++u) hprev[u] = 0.f;

    stage_issue(0);
    stage_write(0);
    project(0);

    auto gate = [](float v) { return __builtin_amdgcn_rcpf(1.f + __expf(-v)); };

    // ---------------- main loop ----------------
    #pragma unroll 1
    for (int ci = 0; ci < NCH; ++ci) {
        const int buf = ci & 1;
        if (ci < NCH - 1) stage_issue(ci + 1);

        // ---- scan 4 steps ----
        #pragma unroll
        for (int tt = 0; tt < 4; ++tt) {
            const int t = ci * 4 + tt;
            const _Float16* pr = &s_pre[buf][tt][s16][0];
            f16x4 p0 = *(const f16x4*)&pr[      4 * q];
            f16x4 p1 = *(const f16x4*)&pr[ 16 + 4 * q];
            f16x4 p2 = *(const f16x4*)&pr[ 32 + 4 * q];
            f16x4 p3 = *(const f16x4*)&pr[ 48 + 4 * q];
            f16x4 p4 = *(const f16x4*)&pr[ 64 + 4 * q];
            f16x4 p5 = *(const f16x4*)&pr[ 80 + 4 * q];
            f16x8 hB = {};
            if (t > 0) hB = *(const f16x8*)&hring[(t - 1) & 3][s16][8 * q];

            f32x4 aR0 = {(float)p0[0], (float)p0[1], (float)p0[2], (float)p0[3]};
            f32x4 aR1 = {(float)p1[0], (float)p1[1], (float)p1[2], (float)p1[3]};
            f32x4 aZ0 = {(float)p2[0], (float)p2[1], (float)p2[2], (float)p2[3]};
            f32x4 aZ1 = {(float)p3[0], (float)p3[1], (float)p3[2], (float)p3[3]};
            f32x4 aN0 = {bhN[0][0], bhN[0][1], bhN[0][2], bhN[0][3]};
            f32x4 aN1 = {bhN[1][0], bhN[1][1], bhN[1][2], bhN[1][3]};
            aR0 = __builtin_amdgcn_mfma_f32_16x16x32_f16(whhA[0], hB, aR0, 0, 0, 0);
            aR1 = __builtin_amdgcn_mfma_f32_16x16x32_f16(whhA[1], hB, aR1, 0, 0, 0);
            aZ0 = __builtin_amdgcn_mfma_f32_16x16x32_f16(whhA[2], hB, aZ0, 0, 0, 0);
            aZ1 = __builtin_amdgcn_mfma_f32_16x16x32_f16(whhA[3], hB, aZ1, 0, 0, 0);
            aN0 = __builtin_amdgcn_mfma_f32_16x16x32_f16(whhA[4], hB, aN0, 0, 0, 0);
            aN1 = __builtin_amdgcn_mfma_f32_16x16x32_f16(whhA[5], hB, aN1, 0, 0, 0);

            float hnew[8];
            #pragma unroll
            for (int r = 0; r < 4; ++r) {
                const float rr = gate(aR0[r]);
                const float zz = gate(aZ0[r]);
                float ta = fmaf(rr, aN0[r], (float)p4[r]);
                ta = fminf(fmaxf(ta, -15.f), 15.f);
                const float e2 = __expf(2.f * ta);
                const float nn = (e2 - 1.f) * __builtin_amdgcn_rcpf(e2 + 1.f);
                hnew[r] = (1.f - zz) * nn + zz * hprev[r];
            }
            #pragma unroll
            for (int r = 0; r < 4; ++r) {
                const float rr = gate(aR1[r]);
                const float zz = gate(aZ1[r]);
                float ta = fmaf(rr, aN1[r], (float)p5[r]);
                ta = fminf(fmaxf(ta, -15.f), 15.f);
                const float e2 = __expf(2.f * ta);
                const float nn = (e2 - 1.f) * __builtin_amdgcn_rcpf(e2 + 1.f);
                hnew[4 + r] = (1.f - zz) * nn + zz * hprev[4 + r];
            }
            uint2 w0; w0.x = pkh(hnew[0], hnew[1]); w0.y = pkh(hnew[2], hnew[3]);
            uint2 w1; w1.x = pkh(hnew[4], hnew[5]); w1.y = pkh(hnew[6], hnew[7]);
            *(uint2*)&hring[t & 3][s16][     4 * q] = w0;
            *(uint2*)&hring[t & 3][s16][16 + 4 * q] = w1;
            #pragma unroll
            for (int u = 0; u < 8; ++u) hprev[u] = hnew[u];
        }

        // ---- cooperative output store for this chunk ----
        {
            const int jj = lane >> 1;
            const int sb = (lane & 1) * 8;
            float* obase = out + (size_t)b * 491520 + (size_t)(d * 32 + jj) * 7680;
            const int wb = d ? (156 - ci * 4) : (ci * 4);
            #pragma unroll
            for (int p = 0; p < 8; ++p) {
                const int s = sb + p;
                float4 v;
                if (d == 0)
                    v = make_float4((float)hring[0][s][jj], (float)hring[1][s][jj],
                                    (float)hring[2][s][jj], (float)hring[3][s][jj]);
                else
                    v = make_float4((float)hring[3][s][jj], (float)hring[2][s][jj],
                                    (float)hring[1][s][jj], (float)hring[0][s][jj]);
                *(float4*)&obase[(h0 + s) * 160 + wb] = v;
            }
        }

        // ---- stage + project next chunk ----
        if (ci < NCH - 1) {
            stage_write(buf ^ 1);
            project(buf ^ 1);
        }
    }
}

extern "C" void kernel_launch(void* const* d_in, const int* in_sizes, int n_in,
                              void* d_out, int out_size, void* d_ws, size_t ws_size,
                              hipStream_t stream) {
    (void)in_sizes; (void)n_in; (void)ws_size; (void)out_size;
    fold_weights<<<dim3(49), dim3(256), 0, stream>>>(
        (const float*)d_in[1],  // conv_w
        (const float*)d_in[2],  // conv_b
        (const float*)d_in[3],  // wih_f
        (const float*)d_in[5],  // bih_f
        (const float*)d_in[6],  // bhh_f
        (const float*)d_in[7],  // wih_b
        (const float*)d_in[9],  // bih_b
        (const float*)d_in[10], // bhh_b
        d_ws);
    gru_fused5<<<dim3(384), dim3(64), 0, stream>>>(
        (const float*)d_in[0],  // x
        (const float*)d_in[4],  // whh_f
        (const float*)d_in[8],  // whh_b
        d_ws,
        (float*)d_out);
}

// Round 7
// 245.481 us; speedup vs baseline: 1.5262x; 1.5262x over previous
//
#include <hip/hip_runtime.h>

// GruBlock round 7: MFMA recurrence with register-recycled h (permuted-whh trick),
// 4-wave blocks: 1 scan wave + 3 helper waves (stage + projection).
// 384 blocks x 256 thr. Block = (b, h-group of 16, dir). Superchunk = 8 w, NSC=20.
// h never leaves registers: C-frag of n-gate tiles == next B-frag under column
// permutation pi folded into whh2 at fold time.

typedef _Float16 f16x8 __attribute__((ext_vector_type(8)));
typedef _Float16 f16x4 __attribute__((ext_vector_type(4)));
typedef __fp16   pk16  __attribute__((ext_vector_type(2)));
typedef float    f32x4 __attribute__((ext_vector_type(4)));

#define HWSTRIDE 7680   // 48*160
#define NSC 20
#define WS_WHH2_OFF 24576
#define WS_BIAS_OFF 36864

__global__ void fold_weights(const float* __restrict__ conv_w,
                             const float* __restrict__ conv_b,
                             const float* __restrict__ wih_f,
                             const float* __restrict__ bih_f,
                             const float* __restrict__ bhh_f,
                             const float* __restrict__ wih_b,
                             const float* __restrict__ bih_b,
                             const float* __restrict__ bhh_b,
                             const float* __restrict__ whh_f,
                             const float* __restrict__ whh_b,
                             void* wsv)
{
    _Float16* W2   = (_Float16*)wsv;
    _Float16* whh2 = (_Float16*)((char*)wsv + WS_WHH2_OFF);
    float*    bias = (float*)((char*)wsv + WS_BIAS_OFF);
    const int idx = blockIdx.x * 256 + threadIdx.x;
    if (idx < 12288) {
        const int d = idx / 6144, r = idx % 6144, g = r / 64, c = r % 64;
        const float* wih = d ? wih_b : wih_f;
        float acc = 0.f;
        for (int o = 0; o < 64; ++o) acc += wih[g * 64 + o] * conv_w[o * 64 + c];
        W2[idx] = (_Float16)acc;
    } else if (idx < 18432) {
        const int e2 = idx - 12288;
        const int dd = e2 / 3072, rr = e2 % 3072, g = rr / 32, k = rr % 32;
        const int qq = k >> 3, ee = k & 7;
        const int jsrc = (ee < 4) ? (qq * 4 + ee) : (16 + qq * 4 + (ee - 4));
        const float* whh = dd ? whh_b : whh_f;
        whh2[e2] = (_Float16)whh[g * 32 + jsrc];
    } else if (idx < 18688) {
        const int e = idx - 18432;
        const int d = e >> 7, rr = e & 127, kind = rr >> 5, j = rr & 31;
        const float* wih = d ? wih_b : wih_f;
        const float* bih = d ? bih_b : bih_f;
        const float* bhh = d ? bhh_b : bhh_f;
        float v;
        if (kind == 0 || kind == 1) {
            const int g = j + kind * 32;
            float b2 = bih[g];
            for (int o = 0; o < 64; ++o) b2 += wih[g * 64 + o] * conv_b[o];
            v = b2 + bhh[g];
        } else if (kind == 2) {
            const int g = j + 64;
            float b2 = bih[g];
            for (int o = 0; o < 64; ++o) b2 += wih[g * 64 + o] * conv_b[o];
            v = b2;
        } else {
            v = bhh[j + 64];
        }
        bias[(d * 4 + kind) * 32 + j] = v;
    }
}

static __device__ __forceinline__ unsigned pkh(float a, float b) {
    pk16 p = __builtin_amdgcn_cvt_pkrtz(a, b);
    return __builtin_bit_cast(unsigned, p);
}

#define BAR() do { asm volatile("s_waitcnt lgkmcnt(0)" ::: "memory"); \
                   __builtin_amdgcn_s_barrier();                      \
                   asm volatile("" ::: "memory"); } while (0)

__global__ __launch_bounds__(256, 2)
void gru_fused6(const float* __restrict__ x,
                const void* __restrict__ wsv,
                float* __restrict__ out)
{
    __shared__ _Float16 xt[1024 * 10];            // 20480 B: [row=c*16+s][8w + 2 pad]
    __shared__ _Float16 spre[2 * 8 * 16 * 100];   // 51200 B: [buf][t][s][96g + 4 pad]

    const int d    = blockIdx.x & 1;
    const int g2   = blockIdx.x >> 1;
    const int b    = g2 / 3;
    const int h0   = (g2 % 3) * 16;
    const int lane = threadIdx.x & 63;
    const int wave = threadIdx.x >> 6;
    const int sw   = blockIdx.x & 3;              // rotating scan wave
    const int rel  = (wave - sw) & 3;
    const int q    = lane >> 4;
    const int s16  = lane & 15;

    const float* xb = x + (size_t)b * 64 * HWSTRIDE + (size_t)h0 * 160;

    if (rel != 0) {
        // ===================== helper waves =====================
        const int hw = rel - 1;                   // 0..2
        const int u  = hw * 64 + lane;            // 0..191
        const int nrows = (u < 64) ? 6 : 5;       // 1024 = 192*5 + 64 (wave-uniform)

        const _Float16* W2 = (const _Float16*)wsv + (size_t)d * 96 * 64;
        f16x8 W2A[6][2];
        #pragma unroll
        for (int gt = 0; gt < 6; ++gt)
            #pragma unroll
            for (int kt = 0; kt < 2; ++kt)
                W2A[gt][kt] = *(const f16x8*)&W2[(gt * 16 + s16) * 64 + kt * 32 + q * 8];
        const float* bias = (const float*)((const char*)wsv + WS_BIAS_OFF) + d * 128;
        float biasC[6][4];
        #pragma unroll
        for (int gt = 0; gt < 6; ++gt)
            #pragma unroll
            for (int r = 0; r < 4; ++r)
                biasC[gt][r] = bias[(gt >> 1) * 32 + (gt & 1) * 16 + 4 * q + r];

        float4 pfA[12], pfB[12];
        auto load_sc = [&](float4 (&pf)[12], int sc) {
            const int w0 = d ? (152 - 8 * sc) : (8 * sc);
            #pragma unroll
            for (int k = 0; k < 6; ++k) {
                if (k < nrows) {
                    const int r = u + 192 * k;
                    const float* p = xb + (size_t)(r >> 4) * HWSTRIDE + (r & 15) * 160 + w0;
                    pf[2 * k]     = *(const float4*)p;
                    pf[2 * k + 1] = *(const float4*)(p + 4);
                }
            }
        };
        auto write_sc = [&](float4 (&pf)[12]) {
            #pragma unroll
            for (int k = 0; k < 6; ++k) {
                if (k < nrows) {
                    const int r = u + 192 * k;
                    const int qsw = (r >> 7) & 1;          // ((c>>3)&1)
                    uint2 a, bq;
                    a.x  = pkh(pf[2*k].x,   pf[2*k].y);   a.y  = pkh(pf[2*k].z,   pf[2*k].w);
                    bq.x = pkh(pf[2*k+1].x, pf[2*k+1].y); bq.y = pkh(pf[2*k+1].z, pf[2*k+1].w);
                    _Float16* rowp = &xt[r * 10];
                    *(uint2*)(rowp + (qsw ? 4 : 0)) = a;   // w-quad 0 -> slot qsw
                    *(uint2*)(rowp + (qsw ? 0 : 4)) = bq;  // w-quad 1 -> slot 1^qsw
                }
            }
        };
        auto project = [&](int sc) {
            const int bufn = sc & 1;
            for (int tt = hw; tt < 8; tt += 3) {
                const int ww = d ? (7 - tt) : tt;
                const int sl = (((ww >> 2) ^ (q & 1)) << 2) + (ww & 3);
                const int base0 = (q * 8 * 16 + s16) * 10 + sl;
                f16x8 B0, B1;
                #pragma unroll
                for (int e = 0; e < 8; ++e) {
                    B0[e] = xt[base0 + e * 160];
                    B1[e] = xt[base0 + e * 160 + 5120];
                }
                #pragma unroll
                for (int gt = 0; gt < 6; ++gt) {
                    f32x4 acc = {biasC[gt][0], biasC[gt][1], biasC[gt][2], biasC[gt][3]};
                    acc = __builtin_amdgcn_mfma_f32_16x16x32_f16(W2A[gt][0], B0, acc, 0, 0, 0);
                    acc = __builtin_amdgcn_mfma_f32_16x16x32_f16(W2A[gt][1], B1, acc, 0, 0, 0);
                    uint2 v; v.x = pkh(acc[0], acc[1]); v.y = pkh(acc[2], acc[3]);
                    *(uint2*)&spre[((bufn * 8 + tt) * 16 + s16) * 100 + gt * 16 + 4 * q] = v;
                }
            }
        };

        // prologue: xt <- sc0; prefetch sc1
        load_sc(pfA, 0);
        write_sc(pfA);
        load_sc(pfB, 1);
        BAR();                       // P1: xt(0) visible to all helpers
        project(0);                  // -> spre[0]
        BAR();                       // B0: spre[0] ready
        for (int i = 0; i < NSC; ++i) {
            if (i + 1 < NSC) {
                if ((i & 1) == 0) {
                    if (i + 2 < NSC) load_sc(pfA, i + 2);
                    write_sc(pfB);
                } else {
                    if (i + 2 < NSC) load_sc(pfB, i + 2);
                    write_sc(pfA);
                }
            }
            BAR();                   // mid: xt(i+1) ready
            if (i + 1 < NSC) project(i + 1);
            BAR();                   // end: spre[(i+1)&1] ready
        }
    } else {
        // ===================== scan wave =====================
        const _Float16* whh2 = (const _Float16*)((const char*)wsv + WS_WHH2_OFF)
                               + (size_t)d * 96 * 32;
        f16x8 whhA[6];
        #pragma unroll
        for (int gt = 0; gt < 6; ++gt)
            whhA[gt] = *(const f16x8*)&whh2[(gt * 16 + s16) * 32 + q * 8];
        const float* bias = (const float*)((const char*)wsv + WS_BIAS_OFF) + d * 128;
        float bhN[2][4];
        #pragma unroll
        for (int jh = 0; jh < 2; ++jh)
            #pragma unroll
            for (int r = 0; r < 4; ++r)
                bhN[jh][r] = bias[96 + jh * 16 + 4 * q + r];

        float* ob = out + ((size_t)b * 64 + d * 32) * HWSTRIDE + (size_t)(h0 + s16) * 160;
        f16x8 hB = {};
        float hprev[8];
        #pragma unroll
        for (int uu = 0; uu < 8; ++uu) hprev[uu] = 0.f;

        BAR();   // P1
        BAR();   // B0

        #pragma unroll 1
        for (int i = 0; i < NSC; ++i) {
            const int buf = i & 1;
            f16x4 pg[4][6];
            float hh[2][4][4];
            #pragma unroll
            for (int tt = 0; tt < 8; ++tt) {
                if ((tt & 3) == 0) {
                    #pragma unroll
                    for (int t4 = 0; t4 < 4; ++t4)
                        #pragma unroll
                        for (int gt = 0; gt < 6; ++gt)
                            pg[t4][gt] = *(const f16x4*)
                                &spre[((buf * 8 + tt + t4) * 16 + s16) * 100 + gt * 16 + 4 * q];
                }
                if (tt == 2) BAR();   // mid barrier (helpers finished xt write)
                const f16x4 p0 = pg[tt & 3][0], p1 = pg[tt & 3][1];
                const f16x4 p2 = pg[tt & 3][2], p3 = pg[tt & 3][3];
                const f16x4 p4 = pg[tt & 3][4], p5 = pg[tt & 3][5];
                f32x4 aR0 = {(float)p0[0], (float)p0[1], (float)p0[2], (float)p0[3]};
                f32x4 aR1 = {(float)p1[0], (float)p1[1], (float)p1[2], (float)p1[3]};
                f32x4 aZ0 = {(float)p2[0], (float)p2[1], (float)p2[2], (float)p2[3]};
                f32x4 aZ1 = {(float)p3[0], (float)p3[1], (float)p3[2], (float)p3[3]};
                f32x4 aN0 = {bhN[0][0], bhN[0][1], bhN[0][2], bhN[0][3]};
                f32x4 aN1 = {bhN[1][0], bhN[1][1], bhN[1][2], bhN[1][3]};
                aR0 = __builtin_amdgcn_mfma_f32_16x16x32_f16(whhA[0], hB, aR0, 0, 0, 0);
                aR1 = __builtin_amdgcn_mfma_f32_16x16x32_f16(whhA[1], hB, aR1, 0, 0, 0);
                aZ0 = __builtin_amdgcn_mfma_f32_16x16x32_f16(whhA[2], hB, aZ0, 0, 0, 0);
                aZ1 = __builtin_amdgcn_mfma_f32_16x16x32_f16(whhA[3], hB, aZ1, 0, 0, 0);
                aN0 = __builtin_amdgcn_mfma_f32_16x16x32_f16(whhA[4], hB, aN0, 0, 0, 0);
                aN1 = __builtin_amdgcn_mfma_f32_16x16x32_f16(whhA[5], hB, aN1, 0, 0, 0);
                float hn[8];
                #pragma unroll
                for (int r = 0; r < 4; ++r) {
                    const float rr = __builtin_amdgcn_rcpf(1.f + __expf(-aR0[r]));
                    const float zz = __builtin_amdgcn_rcpf(1.f + __expf(-aZ0[r]));
                    float ta = fmaf(rr, aN0[r], (float)p4[r]);
                    ta = fminf(fmaxf(ta, -15.f), 15.f);
                    const float e2 = __expf(2.f * ta);
                    const float nn = (e2 - 1.f) * __builtin_amdgcn_rcpf(e2 + 1.f);
                    hn[r] = (1.f - zz) * nn + zz * hprev[r];
                }
                #pragma unroll
                for (int r = 0; r < 4; ++r) {
                    const float rr = __builtin_amdgcn_rcpf(1.f + __expf(-aR1[r]));
                    const float zz = __builtin_amdgcn_rcpf(1.f + __expf(-aZ1[r]));
                    float ta = fmaf(rr, aN1[r], (float)p5[r]);
                    ta = fminf(fmaxf(ta, -15.f), 15.f);
                    const float e2 = __expf(2.f * ta);
                    const float nn = (e2 - 1.f) * __builtin_amdgcn_rcpf(e2 + 1.f);
                    hn[4 + r] = (1.f - zz) * nn + zz * hprev[4 + r];
                }
                {
                    uint4 hu;
                    hu.x = pkh(hn[0], hn[1]); hu.y = pkh(hn[2], hn[3]);
                    hu.z = pkh(hn[4], hn[5]); hu.w = pkh(hn[6], hn[7]);
                    hB = __builtin_bit_cast(f16x8, hu);
                }
                #pragma unroll
                for (int uu = 0; uu < 8; ++uu) hprev[uu] = hn[uu];
                #pragma unroll
                for (int r = 0; r < 4; ++r) {
                    hh[0][r][tt & 3] = hn[r];
                    hh[1][r][tt & 3] = hn[4 + r];
                }
                if (tt == 3 || tt == 7) {
                    const int g = tt >> 2;
                    #pragma unroll
                    for (int jh = 0; jh < 2; ++jh)
                        #pragma unroll
                        for (int r = 0; r < 4; ++r) {
                            const int j = jh * 16 + 4 * q + r;
                            float* pw = ob + (size_t)j * HWSTRIDE;
                            if (d == 0)
                                *(float4*)(pw + i * 8 + g * 4) =
                                    make_float4(hh[jh][r][0], hh[jh][r][1],
                                                hh[jh][r][2], hh[jh][r][3]);
                            else
                                *(float4*)(pw + 156 - i * 8 - g * 4) =
                                    make_float4(hh[jh][r][3], hh[jh][r][2],
                                                hh[jh][r][1], hh[jh][r][0]);
                        }
                }
            }
            BAR();                   // end barrier
        }
    }
}

extern "C" void kernel_launch(void* const* d_in, const int* in_sizes, int n_in,
                              void* d_out, int out_size, void* d_ws, size_t ws_size,
                              hipStream_t stream) {
    (void)in_sizes; (void)n_in; (void)ws_size; (void)out_size;
    fold_weights<<<dim3(74), dim3(256), 0, stream>>>(
        (const float*)d_in[1],  // conv_w
        (const float*)d_in[2],  // conv_b
        (const float*)d_in[3],  // wih_f
        (const float*)d_in[5],  // bih_f
        (const float*)d_in[6],  // bhh_f
        (const float*)d_in[7],  // wih_b
        (const float*)d_in[9],  // bih_b
        (const float*)d_in[10], // bhh_b
        (const float*)d_in[4],  // whh_f
        (const float*)d_in[8],  // whh_b
        d_ws);
    gru_fused6<<<dim3(384), dim3(256), 0, stream>>>(
        (const float*)d_in[0],  // x
        d_ws,
        (float*)d_out);
}

// Round 8
// 214.554 us; speedup vs baseline: 1.7461x; 1.1441x over previous
//
#include <hip/hip_runtime.h>

// GruBlock round 8: full-cache-line memory granularity.
// 384 blocks x 256 thr (1 scan wave + 3 helpers), block = (b, 16 h-rows, dir).
// Window = 16 timesteps: helpers read 64 B/row (full line) per window, project
// pre = W2@x via MFMA into spre (single buffer); scan wave runs 16 GRU steps
// (MFMA recurrence, h register-recycled via permuted whh2) and buffers 16 steps
// of packed h, storing full 64-B lines of out in the next window's phase A.

typedef _Float16 f16x8 __attribute__((ext_vector_type(8)));
typedef _Float16 f16x4 __attribute__((ext_vector_type(4)));
typedef __fp16   pk16  __attribute__((ext_vector_type(2)));
typedef float    f32x4 __attribute__((ext_vector_type(4)));

#define HWSTRIDE 7680   // 48*160
#define NW 10           // 160 / 16
#define WS_WHH2_OFF 24576
#define WS_BIAS_OFF 36864

__global__ void fold_weights(const float* __restrict__ conv_w,
                             const float* __restrict__ conv_b,
                             const float* __restrict__ wih_f,
                             const float* __restrict__ bih_f,
                             const float* __restrict__ bhh_f,
                             const float* __restrict__ wih_b,
                             const float* __restrict__ bih_b,
                             const float* __restrict__ bhh_b,
                             const float* __restrict__ whh_f,
                             const float* __restrict__ whh_b,
                             void* wsv)
{
    _Float16* W2   = (_Float16*)wsv;
    _Float16* whh2 = (_Float16*)((char*)wsv + WS_WHH2_OFF);
    float*    bias = (float*)((char*)wsv + WS_BIAS_OFF);
    const int idx = blockIdx.x * 256 + threadIdx.x;
    if (idx < 12288) {
        const int d = idx / 6144, r = idx % 6144, g = r / 64, c = r % 64;
        const float* wih = d ? wih_b : wih_f;
        float acc = 0.f;
        for (int o = 0; o < 64; ++o) acc += wih[g * 64 + o] * conv_w[o * 64 + c];
        W2[idx] = (_Float16)acc;
    } else if (idx < 18432) {
        const int e2 = idx - 12288;
        const int dd = e2 / 3072, rr = e2 % 3072, g = rr / 32, k = rr % 32;
        const int qq = k >> 3, ee = k & 7;
        const int jsrc = (ee < 4) ? (qq * 4 + ee) : (16 + qq * 4 + (ee - 4));
        const float* whh = dd ? whh_b : whh_f;
        whh2[e2] = (_Float16)whh[g * 32 + jsrc];
    } else if (idx < 18688) {
        const int e = idx - 18432;
        const int d = e >> 7, rr = e & 127, kind = rr >> 5, j = rr & 31;
        const float* wih = d ? wih_b : wih_f;
        const float* bih = d ? bih_b : bih_f;
        const float* bhh = d ? bhh_b : bhh_f;
        float v;
        if (kind == 0 || kind == 1) {
            const int g = j + kind * 32;
            float b2 = bih[g];
            for (int o = 0; o < 64; ++o) b2 += wih[g * 64 + o] * conv_b[o];
            v = b2 + bhh[g];
        } else if (kind == 2) {
            const int g = j + 64;
            float b2 = bih[g];
            for (int o = 0; o < 64; ++o) b2 += wih[g * 64 + o] * conv_b[o];
            v = b2;
        } else {
            v = bhh[j + 64];
        }
        bias[(d * 4 + kind) * 32 + j] = v;
    }
}

static __device__ __forceinline__ unsigned pkh(float a, float b) {
    pk16 p = __builtin_amdgcn_cvt_pkrtz(a, b);
    return __builtin_bit_cast(unsigned, p);
}

#define BAR() do { asm volatile("s_waitcnt lgkmcnt(0)" ::: "memory"); \
                   __builtin_amdgcn_s_barrier();                      \
                   asm volatile("" ::: "memory"); } while (0)

__global__ __launch_bounds__(256, 2)
void gru_fused7(const float* __restrict__ x,
                const void* __restrict__ wsv,
                float* __restrict__ out)
{
    __shared__ __align__(16) _Float16 xt[1024 * 16];      // 32768 B [row=c*16+s][16w swz]
    __shared__ __align__(16) _Float16 spre[16 * 16 * 96]; // 49152 B [t][s][96g swz]

    const int d    = blockIdx.x & 1;
    const int g2   = blockIdx.x >> 1;
    const int b    = g2 / 3;
    const int h0   = (g2 % 3) * 16;
    const int lane = threadIdx.x & 63;
    const int wave = threadIdx.x >> 6;
    const int sw   = blockIdx.x & 3;
    const int rel  = (wave - sw) & 3;
    const int q    = lane >> 4;
    const int s16  = lane & 15;

    const float* xb = x + (size_t)b * 64 * HWSTRIDE + (size_t)h0 * 160;

    if (rel != 0) {
        // ===================== helper waves =====================
        const int hw = rel - 1;            // 0..2
        const int u  = hw * 64 + lane;     // 0..191
        const int nq = (hw == 0) ? 22 : 21;

        const _Float16* W2 = (const _Float16*)wsv + (size_t)d * 96 * 64;
        f16x8 W2A[6][2];
        #pragma unroll
        for (int gt = 0; gt < 6; ++gt)
            #pragma unroll
            for (int kt = 0; kt < 2; ++kt)
                W2A[gt][kt] = *(const f16x8*)&W2[(gt * 16 + s16) * 64 + kt * 32 + q * 8];
        const float* bias = (const float*)((const char*)wsv + WS_BIAS_OFF) + d * 128;
        float biasC[6][4];
        #pragma unroll
        for (int gt = 0; gt < 6; ++gt)
            #pragma unroll
            for (int r = 0; r < 4; ++r)
                biasC[gt][r] = bias[(gt >> 1) * 32 + (gt & 1) * 16 + 4 * q + r];

        const int xsw = ((s16 >> 2) & 3) << 2;   // xt read swizzle (uniform over e,q)

        float4 pf[22];
        auto load_win = [&](int wi) {
            const int w0 = d ? (144 - 16 * wi) : (16 * wi);
            #pragma unroll
            for (int k = 0; k < 22; ++k) {
                if (k < nq) {
                    const int qd = u + 192 * k;
                    const int row = qd >> 2, m = qd & 3;
                    pf[k] = *(const float4*)(xb + (size_t)(row >> 4) * HWSTRIDE
                                             + (row & 15) * 160 + w0 + m * 4);
                }
            }
        };
        auto write_win = [&]() {
            #pragma unroll
            for (int k = 0; k < 22; ++k) {
                if (k < nq) {
                    const int qd = u + 192 * k;
                    const int row = qd >> 2, m = qd & 3;
                    const int wblk = (m * 4) ^ (((row >> 2) & 3) << 2);
                    uint2 v; v.x = pkh(pf[k].x, pf[k].y); v.y = pkh(pf[k].z, pf[k].w);
                    *(uint2*)&xt[row * 16 + wblk] = v;
                }
            }
        };
        auto project = [&]() {
            for (int tt = hw; tt < 16; tt += 3) {
                const int wl = d ? (15 - tt) : tt;
                const int wsel = wl ^ xsw;
                const int base0 = (q * 128 + s16) * 16 + wsel;
                f16x8 B0, B1;
                #pragma unroll
                for (int e = 0; e < 8; ++e) {
                    B0[e] = xt[base0 + e * 256];
                    B1[e] = xt[base0 + e * 256 + 8192];
                }
                #pragma unroll
                for (int gt = 0; gt < 6; ++gt) {
                    f32x4 acc = {biasC[gt][0], biasC[gt][1], biasC[gt][2], biasC[gt][3]};
                    acc = __builtin_amdgcn_mfma_f32_16x16x32_f16(W2A[gt][0], B0, acc, 0, 0, 0);
                    acc = __builtin_amdgcn_mfma_f32_16x16x32_f16(W2A[gt][1], B1, acc, 0, 0, 0);
                    uint2 v; v.x = pkh(acc[0], acc[1]); v.y = pkh(acc[2], acc[3]);
                    const int col = (gt * 16 + 4 * q) ^ ((s16 & 7) << 2);
                    *(uint2*)&spre[(tt * 16 + s16) * 96 + col] = v;
                }
            }
        };

        // prologue
        load_win(0);
        write_win();
        load_win(1);
        BAR();
        for (int i = 0; i < NW; ++i) {
            project();               // window i: xt -> spre
            BAR();                   // BAR1
            if (i + 1 < NW) {
                write_win();         // xt <- window i+1
                if (i + 2 < NW) load_win(i + 2);
            }
            BAR();                   // BAR2
        }
    } else {
        // ===================== scan wave =====================
        const _Float16* whh2 = (const _Float16*)((const char*)wsv + WS_WHH2_OFF)
                               + (size_t)d * 96 * 32;
        f16x8 whhA[6];
        #pragma unroll
        for (int gt = 0; gt < 6; ++gt)
            whhA[gt] = *(const f16x8*)&whh2[(gt * 16 + s16) * 32 + q * 8];
        const float* bias = (const float*)((const char*)wsv + WS_BIAS_OFF) + d * 128;
        float bhN[2][4];
        #pragma unroll
        for (int jh = 0; jh < 2; ++jh)
            #pragma unroll
            for (int r = 0; r < 4; ++r)
                bhN[jh][r] = bias[96 + jh * 16 + 4 * q + r];

        float* ob = out + ((size_t)b * 64 + d * 32) * HWSTRIDE + (size_t)(h0 + s16) * 160;
        f16x8 hB = {};
        f16x8 hB16[16];
        float hprev[8];
        #pragma unroll
        for (int uu = 0; uu < 8; ++uu) hprev[uu] = 0.f;

        int spcol[6];
        #pragma unroll
        for (int gt = 0; gt < 6; ++gt)
            spcol[gt] = (gt * 16 + 4 * q) ^ ((s16 & 7) << 2);

        auto store_win = [&](int wi) {
            const int wbase = d ? (144 - 16 * wi) : (16 * wi);
            #pragma unroll
            for (int e = 0; e < 8; ++e) {
                const int j = (e >> 2) * 16 + 4 * q + (e & 3);
                float* pw = ob + (size_t)j * HWSTRIDE + wbase;
                #pragma unroll
                for (int m = 0; m < 4; ++m) {
                    float4 v;
                    if (d == 0)
                        v = make_float4((float)hB16[4*m][e],   (float)hB16[4*m+1][e],
                                        (float)hB16[4*m+2][e], (float)hB16[4*m+3][e]);
                    else
                        v = make_float4((float)hB16[15-4*m][e], (float)hB16[14-4*m][e],
                                        (float)hB16[13-4*m][e], (float)hB16[12-4*m][e]);
                    *(float4*)(pw + 4 * m) = v;
                }
            }
        };

        BAR();   // prologue
        #pragma unroll 1
        for (int i = 0; i < NW; ++i) {
            if (i > 0) store_win(i - 1);
            BAR();                   // BAR1: spre(i) ready
            f16x4 pg[4][6];
            #pragma unroll
            for (int tt = 0; tt < 16; ++tt) {
                if ((tt & 3) == 0) {
                    #pragma unroll
                    for (int t4 = 0; t4 < 4; ++t4)
                        #pragma unroll
                        for (int gt = 0; gt < 6; ++gt)
                            pg[t4][gt] = *(const f16x4*)
                                &spre[((tt + t4) * 16 + s16) * 96 + spcol[gt]];
                }
                const f16x4 p0 = pg[tt & 3][0], p1 = pg[tt & 3][1];
                const f16x4 p2 = pg[tt & 3][2], p3 = pg[tt & 3][3];
                const f16x4 p4 = pg[tt & 3][4], p5 = pg[tt & 3][5];
                f32x4 aR0 = {(float)p0[0], (float)p0[1], (float)p0[2], (float)p0[3]};
                f32x4 aR1 = {(float)p1[0], (float)p1[1], (float)p1[2], (float)p1[3]};
                f32x4 aZ0 = {(float)p2[0], (float)p2[1], (float)p2[2], (float)p2[3]};
                f32x4 aZ1 = {(float)p3[0], (float)p3[1], (float)p3[2], (float)p3[3]};
                f32x4 aN0 = {bhN[0][0], bhN[0][1], bhN[0][2], bhN[0][3]};
                f32x4 aN1 = {bhN[1][0], bhN[1][1], bhN[1][2], bhN[1][3]};
                aR0 = __builtin_amdgcn_mfma_f32_16x16x32_f16(whhA[0], hB, aR0, 0, 0, 0);
                aR1 = __builtin_amdgcn_mfma_f32_16x16x32_f16(whhA[1], hB, aR1, 0, 0, 0);
                aZ0 = __builtin_amdgcn_mfma_f32_16x16x32_f16(whhA[2], hB, aZ0, 0, 0, 0);
                aZ1 = __builtin_amdgcn_mfma_f32_16x16x32_f16(whhA[3], hB, aZ1, 0, 0, 0);
                aN0 = __builtin_amdgcn_mfma_f32_16x16x32_f16(whhA[4], hB, aN0, 0, 0, 0);
                aN1 = __builtin_amdgcn_mfma_f32_16x16x32_f16(whhA[5], hB, aN1, 0, 0, 0);
                float hn[8];
                #pragma unroll
                for (int r = 0; r < 4; ++r) {
                    const float rr = __builtin_amdgcn_rcpf(1.f + __expf(-aR0[r]));
                    const float zz = __builtin_amdgcn_rcpf(1.f + __expf(-aZ0[r]));
                    float ta = fmaf(rr, aN0[r], (float)p4[r]);
                    ta = fminf(fmaxf(ta, -15.f), 15.f);
                    const float e2 = __expf(2.f * ta);
                    const float nn = (e2 - 1.f) * __builtin_amdgcn_rcpf(e2 + 1.f);
                    hn[r] = (1.f - zz) * nn + zz * hprev[r];
                }
                #pragma unroll
                for (int r = 0; r < 4; ++r) {
                    const float rr = __builtin_amdgcn_rcpf(1.f + __expf(-aR1[r]));
                    const float zz = __builtin_amdgcn_rcpf(1.f + __expf(-aZ1[r]));
                    float ta = fmaf(rr, aN1[r], (float)p5[r]);
                    ta = fminf(fmaxf(ta, -15.f), 15.f);
                    const float e2 = __expf(2.f * ta);
                    const float nn = (e2 - 1.f) * __builtin_amdgcn_rcpf(e2 + 1.f);
                    hn[4 + r] = (1.f - zz) * nn + zz * hprev[4 + r];
                }
                {
                    uint4 hu;
                    hu.x = pkh(hn[0], hn[1]); hu.y = pkh(hn[2], hn[3]);
                    hu.z = pkh(hn[4], hn[5]); hu.w = pkh(hn[6], hn[7]);
                    hB = __builtin_bit_cast(f16x8, hu);
                }
                hB16[tt] = hB;
                #pragma unroll
                for (int uu = 0; uu < 8; ++uu) hprev[uu] = hn[uu];
            }
            BAR();                   // BAR2
        }
        store_win(NW - 1);
    }
}

extern "C" void kernel_launch(void* const* d_in, const int* in_sizes, int n_in,
                              void* d_out, int out_size, void* d_ws, size_t ws_size,
                              hipStream_t stream) {
    (void)in_sizes; (void)n_in; (void)ws_size; (void)out_size;
    fold_weights<<<dim3(74), dim3(256), 0, stream>>>(
        (const float*)d_in[1],  // conv_w
        (const float*)d_in[2],  // conv_b
        (const float*)d_in[3],  // wih_f
        (const float*)d_in[5],  // bih_f
        (const float*)d_in[6],  // bhh_f
        (const float*)d_in[7],  // wih_b
        (const float*)d_in[9],  // bih_b
        (const float*)d_in[10], // bhh_b
        (const float*)d_in[4],  // whh_f
        (const float*)d_in[8],  // whh_b
        d_ws);
    gru_fused7<<<dim3(384), dim3(256), 0, stream>>>(
        (const float*)d_in[0],  // x
        d_ws,
        (float*)d_out);
}

// Round 9
// 183.040 us; speedup vs baseline: 2.0468x; 1.1722x over previous
//
#include <hip/hip_runtime.h>

// GruBlock round 9: producer-consumer 2-wave blocks, double-buffered spre.
// 384 blocks x 128 thr. Block = (16 seqs, dir). Window = 8 timesteps, NW = 20.
// Helper wave: stage x (f16, full-line loads) -> xt; project pre = W2@x via
// MFMA -> spre[i&1]; issue next window's loads; barrier. Runs 1 window ahead.
// Scan wave: per window, 8 GRU steps (MFMA recurrence, h register-recycled via
// permuted whh2) reading spre[i&1]; full 32B-line output stores.
// Barriers are lgkm-only (global loads stay in flight across them).

typedef _Float16 f16x8 __attribute__((ext_vector_type(8)));
typedef _Float16 f16x4 __attribute__((ext_vector_type(4)));
typedef __fp16   pk16  __attribute__((ext_vector_type(2)));
typedef float    f32x4 __attribute__((ext_vector_type(4)));

#define HWSTRIDE 7680   // 48*160
#define NW 20           // 160 / 8
#define WS_WHH2_OFF 24576
#define WS_BIAS_OFF 36864

__global__ void fold_weights(const float* __restrict__ conv_w,
                             const float* __restrict__ conv_b,
                             const float* __restrict__ wih_f,
                             const float* __restrict__ bih_f,
                             const float* __restrict__ bhh_f,
                             const float* __restrict__ wih_b,
                             const float* __restrict__ bih_b,
                             const float* __restrict__ bhh_b,
                             const float* __restrict__ whh_f,
                             const float* __restrict__ whh_b,
                             void* wsv)
{
    _Float16* W2   = (_Float16*)wsv;
    _Float16* whh2 = (_Float16*)((char*)wsv + WS_WHH2_OFF);
    float*    bias = (float*)((char*)wsv + WS_BIAS_OFF);
    const int idx = blockIdx.x * 256 + threadIdx.x;
    if (idx < 12288) {
        const int d = idx / 6144, r = idx % 6144, g = r / 64, c = r % 64;
        const float* wih = d ? wih_b : wih_f;
        float acc = 0.f;
        for (int o = 0; o < 64; ++o) acc += wih[g * 64 + o] * conv_w[o * 64 + c];
        W2[idx] = (_Float16)acc;
    } else if (idx < 18432) {
        const int e2 = idx - 12288;
        const int dd = e2 / 3072, rr = e2 % 3072, g = rr / 32, k = rr % 32;
        const int qq = k >> 3, ee = k & 7;
        const int jsrc = (ee < 4) ? (qq * 4 + ee) : (16 + qq * 4 + (ee - 4));
        const float* whh = dd ? whh_b : whh_f;
        whh2[e2] = (_Float16)whh[g * 32 + jsrc];
    } else if (idx < 18688) {
        const int e = idx - 18432;
        const int d = e >> 7, rr = e & 127, kind = rr >> 5, j = rr & 31;
        const float* wih = d ? wih_b : wih_f;
        const float* bih = d ? bih_b : bih_f;
        const float* bhh = d ? bhh_b : bhh_f;
        float v;
        if (kind == 0 || kind == 1) {
            const int g = j + kind * 32;
            float b2 = bih[g];
            for (int o = 0; o < 64; ++o) b2 += wih[g * 64 + o] * conv_b[o];
            v = b2 + bhh[g];
        } else if (kind == 2) {
            const int g = j + 64;
            float b2 = bih[g];
            for (int o = 0; o < 64; ++o) b2 += wih[g * 64 + o] * conv_b[o];
            v = b2;
        } else {
            v = bhh[j + 64];
        }
        bias[(d * 4 + kind) * 32 + j] = v;
    }
}

static __device__ __forceinline__ unsigned pkh(float a, float b) {
    pk16 p = __builtin_amdgcn_cvt_pkrtz(a, b);
    return __builtin_bit_cast(unsigned, p);
}

#define BAR() do { asm volatile("s_waitcnt lgkmcnt(0)" ::: "memory"); \
                   __builtin_amdgcn_s_barrier();                      \
                   asm volatile("" ::: "memory"); } while (0)

__global__ __launch_bounds__(128, 1)
void gru_fused8(const float* __restrict__ x,
                const void* __restrict__ wsv,
                float* __restrict__ out)
{
    __shared__ __align__(16) _Float16 xt[1024 * 8];      // 16384 B [row=c*16+s][8w]
    __shared__ __align__(16) _Float16 spre[2 * 8 * 16 * 96]; // 49152 B [buf][t][s][96 swz]

    const int bid  = blockIdx.x;
    const int d    = bid / 192;          // dir (fwd block g and bwd block g are 192 apart -> same XCD)
    const int g    = bid % 192;
    const int b    = g / 3;
    const int h0   = (g % 3) * 16;
    const int lane = threadIdx.x & 63;
    const int wave = threadIdx.x >> 6;
    const int sw   = bid & 1;            // rotate scan wave
    const int q    = lane >> 4;
    const int s16  = lane & 15;

    const float* xb = x + (size_t)b * 64 * HWSTRIDE + (size_t)h0 * 160;

    if (wave != sw) {
        // ===================== helper wave =====================
        const _Float16* W2 = (const _Float16*)wsv + (size_t)d * 96 * 64;
        f16x8 W2A[6][2];
        #pragma unroll
        for (int gt = 0; gt < 6; ++gt)
            #pragma unroll
            for (int kt = 0; kt < 2; ++kt)
                W2A[gt][kt] = *(const f16x8*)&W2[(gt * 16 + s16) * 64 + kt * 32 + q * 8];
        const float* bias = (const float*)((const char*)wsv + WS_BIAS_OFF) + d * 128;
        float biasC[6][4];
        #pragma unroll
        for (int gt = 0; gt < 6; ++gt)
            #pragma unroll
            for (int r = 0; r < 4; ++r)
                biasC[gt][r] = bias[(gt >> 1) * 32 + (gt & 1) * 16 + 4 * q + r];

        float4 pf[32];
        auto load_win = [&](int wi) {
            const int w0 = d ? (152 - 8 * wi) : (8 * wi);
            #pragma unroll
            for (int k = 0; k < 16; ++k) {
                const int row = lane + 64 * k;          // (c,s) row
                const float* p = xb + (size_t)(row >> 4) * HWSTRIDE + (row & 15) * 160 + w0;
                pf[2 * k]     = *(const float4*)p;
                pf[2 * k + 1] = *(const float4*)(p + 4);
            }
        };
        auto write_xt = [&]() {
            #pragma unroll
            for (int k = 0; k < 16; ++k) {
                const int row = lane + 64 * k;
                uint4 v;
                v.x = pkh(pf[2*k].x,   pf[2*k].y);
                v.y = pkh(pf[2*k].z,   pf[2*k].w);
                v.z = pkh(pf[2*k+1].x, pf[2*k+1].y);
                v.w = pkh(pf[2*k+1].z, pf[2*k+1].w);
                *(uint4*)&xt[row * 8] = v;
            }
        };
        auto project = [&](int wi) {
            _Float16* sp = &spre[(wi & 1) * 12288];
            for (int tt = 0; tt < 8; ++tt) {
                const int wl = d ? (7 - tt) : tt;
                const int base0 = (q * 8) * 128 + s16 * 8 + wl;
                f16x8 B0, B1;
                #pragma unroll
                for (int e = 0; e < 8; ++e) {
                    B0[e] = xt[base0 + e * 128];
                    B1[e] = xt[base0 + e * 128 + 4096];
                }
                #pragma unroll
                for (int gt = 0; gt < 6; ++gt) {
                    f32x4 acc = {biasC[gt][0], biasC[gt][1], biasC[gt][2], biasC[gt][3]};
                    acc = __builtin_amdgcn_mfma_f32_16x16x32_f16(W2A[gt][0], B0, acc, 0, 0, 0);
                    acc = __builtin_amdgcn_mfma_f32_16x16x32_f16(W2A[gt][1], B1, acc, 0, 0, 0);
                    uint2 v; v.x = pkh(acc[0], acc[1]); v.y = pkh(acc[2], acc[3]);
                    const int col = (gt * 16 + 4 * q) ^ ((s16 & 7) << 2);
                    *(uint2*)&sp[(tt * 16 + s16) * 96 + col] = v;
                }
            }
        };

        load_win(0);
        #pragma unroll 1
        for (int i = 0; i < NW; ++i) {
            write_xt();                    // consume pf (vmcnt auto-wait)
            project(i);                    // xt -> spre[i&1]
            if (i + 1 < NW) load_win(i + 1);  // loads stay in flight across BAR
            BAR();
        }
    } else {
        // ===================== scan wave =====================
        const _Float16* whh2 = (const _Float16*)((const char*)wsv + WS_WHH2_OFF)
                               + (size_t)d * 96 * 32;
        f16x8 whhA[6];
        #pragma unroll
        for (int gt = 0; gt < 6; ++gt)
            whhA[gt] = *(const f16x8*)&whh2[(gt * 16 + s16) * 32 + q * 8];
        const float* bias = (const float*)((const char*)wsv + WS_BIAS_OFF) + d * 128;
        float bhN[2][4];
        #pragma unroll
        for (int jh = 0; jh < 2; ++jh)
            #pragma unroll
            for (int r = 0; r < 4; ++r)
                bhN[jh][r] = bias[96 + jh * 16 + 4 * q + r];

        float* ob = out + ((size_t)b * 64 + d * 32) * HWSTRIDE + (size_t)(h0 + s16) * 160;
        f16x8 hB = {};
        f16x8 hB8[8];
        float hprev[8];
        #pragma unroll
        for (int uu = 0; uu < 8; ++uu) hprev[uu] = 0.f;

        int spcol[6];
        #pragma unroll
        for (int gt = 0; gt < 6; ++gt)
            spcol[gt] = (gt * 16 + 4 * q) ^ ((s16 & 7) << 2);

        #pragma unroll 1
        for (int i = 0; i < NW; ++i) {
            BAR();                         // spre[i&1] ready
            const _Float16* sp = &spre[(i & 1) * 12288];
            f16x4 pg[4][6];
            #pragma unroll
            for (int tt = 0; tt < 8; ++tt) {
                if ((tt & 3) == 0) {
                    #pragma unroll
                    for (int t4 = 0; t4 < 4; ++t4)
                        #pragma unroll
                        for (int gt = 0; gt < 6; ++gt)
                            pg[t4][gt] = *(const f16x4*)
                                &sp[((tt + t4) * 16 + s16) * 96 + spcol[gt]];
                }
                const f16x4 p0 = pg[tt & 3][0], p1 = pg[tt & 3][1];
                const f16x4 p2 = pg[tt & 3][2], p3 = pg[tt & 3][3];
                const f16x4 p4 = pg[tt & 3][4], p5 = pg[tt & 3][5];
                f32x4 aR0 = {(float)p0[0], (float)p0[1], (float)p0[2], (float)p0[3]};
                f32x4 aR1 = {(float)p1[0], (float)p1[1], (float)p1[2], (float)p1[3]};
                f32x4 aZ0 = {(float)p2[0], (float)p2[1], (float)p2[2], (float)p2[3]};
                f32x4 aZ1 = {(float)p3[0], (float)p3[1], (float)p3[2], (float)p3[3]};
                f32x4 aN0 = {bhN[0][0], bhN[0][1], bhN[0][2], bhN[0][3]};
                f32x4 aN1 = {bhN[1][0], bhN[1][1], bhN[1][2], bhN[1][3]};
                aR0 = __builtin_amdgcn_mfma_f32_16x16x32_f16(whhA[0], hB, aR0, 0, 0, 0);
                aR1 = __builtin_amdgcn_mfma_f32_16x16x32_f16(whhA[1], hB, aR1, 0, 0, 0);
                aZ0 = __builtin_amdgcn_mfma_f32_16x16x32_f16(whhA[2], hB, aZ0, 0, 0, 0);
                aZ1 = __builtin_amdgcn_mfma_f32_16x16x32_f16(whhA[3], hB, aZ1, 0, 0, 0);
                aN0 = __builtin_amdgcn_mfma_f32_16x16x32_f16(whhA[4], hB, aN0, 0, 0, 0);
                aN1 = __builtin_amdgcn_mfma_f32_16x16x32_f16(whhA[5], hB, aN1, 0, 0, 0);
                float hn[8];
                #pragma unroll
                for (int r = 0; r < 4; ++r) {
                    const float rr = __builtin_amdgcn_rcpf(1.f + __expf(-aR0[r]));
                    const float zz = __builtin_amdgcn_rcpf(1.f + __expf(-aZ0[r]));
                    float ta = fmaf(rr, aN0[r], (float)p4[r]);
                    ta = fminf(fmaxf(ta, -15.f), 15.f);
                    const float e2 = __expf(2.f * ta);
                    const float nn = (e2 - 1.f) * __builtin_amdgcn_rcpf(e2 + 1.f);
                    hn[r] = (1.f - zz) * nn + zz * hprev[r];
                }
                #pragma unroll
                for (int r = 0; r < 4; ++r) {
                    const float rr = __builtin_amdgcn_rcpf(1.f + __expf(-aR1[r]));
                    const float zz = __builtin_amdgcn_rcpf(1.f + __expf(-aZ1[r]));
                    float ta = fmaf(rr, aN1[r], (float)p5[r]);
                    ta = fminf(fmaxf(ta, -15.f), 15.f);
                    const float e2 = __expf(2.f * ta);
                    const float nn = (e2 - 1.f) * __builtin_amdgcn_rcpf(e2 + 1.f);
                    hn[4 + r] = (1.f - zz) * nn + zz * hprev[4 + r];
                }
                {
                    uint4 hu;
                    hu.x = pkh(hn[0], hn[1]); hu.y = pkh(hn[2], hn[3]);
                    hu.z = pkh(hn[4], hn[5]); hu.w = pkh(hn[6], hn[7]);
                    hB = __builtin_bit_cast(f16x8, hu);
                }
                hB8[tt] = hB;
                #pragma unroll
                for (int uu = 0; uu < 8; ++uu) hprev[uu] = hn[uu];
            }
            // ---- store window i: full 32B per out-row ----
            {
                const int w0 = d ? (152 - 8 * i) : (8 * i);
                #pragma unroll
                for (int e = 0; e < 8; ++e) {
                    const int j = (e >> 2) * 16 + 4 * q + (e & 3);
                    float* pw = ob + (size_t)j * HWSTRIDE + w0;
                    if (d == 0) {
                        *(float4*)(pw) = make_float4((float)hB8[0][e], (float)hB8[1][e],
                                                     (float)hB8[2][e], (float)hB8[3][e]);
                        *(float4*)(pw + 4) = make_float4((float)hB8[4][e], (float)hB8[5][e],
                                                         (float)hB8[6][e], (float)hB8[7][e]);
                    } else {
                        *(float4*)(pw) = make_float4((float)hB8[7][e], (float)hB8[6][e],
                                                     (float)hB8[5][e], (float)hB8[4][e]);
                        *(float4*)(pw + 4) = make_float4((float)hB8[3][e], (float)hB8[2][e],
                                                         (float)hB8[1][e], (float)hB8[0][e]);
                    }
                }
            }
        }
    }
}

extern "C" void kernel_launch(void* const* d_in, const int* in_sizes, int n_in,
                              void* d_out, int out_size, void* d_ws, size_t ws_size,
                              hipStream_t stream) {
    (void)in_sizes; (void)n_in; (void)ws_size; (void)out_size;
    fold_weights<<<dim3(74), dim3(256), 0, stream>>>(
        (const float*)d_in[1],  // conv_w
        (const float*)d_in[2],  // conv_b
        (const float*)d_in[3],  // wih_f
        (const float*)d_in[5],  // bih_f
        (const float*)d_in[6],  // bhh_f
        (const float*)d_in[7],  // wih_b
        (const float*)d_in[9],  // bih_b
        (const float*)d_in[10], // bhh_b
        (const float*)d_in[4],  // whh_f
        (const float*)d_in[8],  // whh_b
        d_ws);
    gru_fused8<<<dim3(384), dim3(128), 0, stream>>>(
        (const float*)d_in[0],  // x
        d_ws,
        (float*)d_out);
}